// Round 1
// baseline (4974.524 us; speedup 1.0000x reference)
//
#include <hip/hip_runtime.h>
#include <hip/hip_bf16.h>
#include <math.h>

#define SEQ 2048
#define DMODEL 1024
#define QH 16
#define KVH 4
#define DH 64
#define TOPK 64

// ---------------- monotone float<->uint mapping for radix select ----------------
__device__ __forceinline__ unsigned f2u(float f) {
    unsigned u = __float_as_uint(f);
    return (u & 0x80000000u) ? ~u : (u | 0x80000000u);
}
__device__ __forceinline__ float u2f(unsigned u) {
    unsigned v = (u & 0x80000000u) ? (u & 0x7fffffffu) : ~u;
    return __uint_as_float(v);
}

// ---------------- tiled f32 GEMM: C[M,N] = A[M,K] * B[N,K]^T ----------------
__global__ __launch_bounds__(256) void gemm_abT(const float* __restrict__ A,
                                                const float* __restrict__ B,
                                                float* __restrict__ C,
                                                int M, int N, int K) {
    __shared__ float As[16][68];
    __shared__ float Bs[16][68];
    const int tid = threadIdx.x;
    const int m0 = blockIdx.y * 64;
    const int n0 = blockIdx.x * 64;
    const int lr = tid >> 2;          // 0..63
    const int lk = (tid & 3) << 2;    // 0,4,8,12
    const int tx = tid & 15;
    const int ty = tid >> 4;

    float acc[4][4];
#pragma unroll
    for (int a = 0; a < 4; ++a)
#pragma unroll
        for (int b = 0; b < 4; ++b) acc[a][b] = 0.f;

    const float* Ap = A + (size_t)(m0 + lr) * K + lk;
    const float* Bp = B + (size_t)(n0 + lr) * K + lk;

    for (int k0 = 0; k0 < K; k0 += 16) {
        float4 a4 = *(const float4*)(Ap + k0);
        float4 b4 = *(const float4*)(Bp + k0);
        As[lk + 0][lr] = a4.x; As[lk + 1][lr] = a4.y;
        As[lk + 2][lr] = a4.z; As[lk + 3][lr] = a4.w;
        Bs[lk + 0][lr] = b4.x; Bs[lk + 1][lr] = b4.y;
        Bs[lk + 2][lr] = b4.z; Bs[lk + 3][lr] = b4.w;
        __syncthreads();
#pragma unroll
        for (int kk = 0; kk < 16; ++kk) {
            float a0 = As[kk][ty * 4 + 0], a1 = As[kk][ty * 4 + 1];
            float a2 = As[kk][ty * 4 + 2], a3 = As[kk][ty * 4 + 3];
            float b0 = Bs[kk][tx * 4 + 0], b1 = Bs[kk][tx * 4 + 1];
            float b2 = Bs[kk][tx * 4 + 2], b3 = Bs[kk][tx * 4 + 3];
            acc[0][0] += a0 * b0; acc[0][1] += a0 * b1; acc[0][2] += a0 * b2; acc[0][3] += a0 * b3;
            acc[1][0] += a1 * b0; acc[1][1] += a1 * b1; acc[1][2] += a1 * b2; acc[1][3] += a1 * b3;
            acc[2][0] += a2 * b0; acc[2][1] += a2 * b1; acc[2][2] += a2 * b2; acc[2][3] += a2 * b3;
            acc[3][0] += a3 * b0; acc[3][1] += a3 * b1; acc[3][2] += a3 * b2; acc[3][3] += a3 * b3;
        }
        __syncthreads();
    }
#pragma unroll
    for (int ii = 0; ii < 4; ++ii)
#pragma unroll
        for (int jj = 0; jj < 4; ++jj)
            C[(size_t)(m0 + ty * 4 + ii) * N + n0 + tx * 4 + jj] = acc[ii][jj];
}

// ---------------- RoPE on q, in place. one thread per (t, head, d<32) pair ----------------
__global__ __launch_bounds__(256) void rope_q_kernel(float* __restrict__ q) {
    int idx = blockIdx.x * 256 + threadIdx.x;
    if (idx >= SEQ * QH * 32) return;
    int t = idx >> 9;              // /(16*32)
    int rem = idx & 511;
    int head = rem >> 5;
    int d = rem & 31;
    float inv = powf(10000.0f, -(float)d * (1.0f / 32.0f));
    float ang = (float)t * inv;
    float s, c;
    sincosf(ang, &s, &c);
    float* p = q + (size_t)t * DMODEL + head * DH + d;
    float lo = p[0], hi = p[32];
    p[0] = lo * c - hi * s;
    p[32] = hi * c + lo * s;
}

// ---------------- RoPE on k + transpose to kT[(head*64+d)][t] ----------------
__global__ __launch_bounds__(256) void rope_k_t_kernel(const float* __restrict__ ktmp,
                                                       float* __restrict__ kT) {
    int idx = blockIdx.x * 256 + threadIdx.x;
    if (idx >= SEQ * KVH * 32) return;
    int t = idx >> 7;              // /(4*32)
    int rem = idx & 127;
    int head = rem >> 5;
    int d = rem & 31;
    float inv = powf(10000.0f, -(float)d * (1.0f / 32.0f));
    float ang = (float)t * inv;
    float s, c;
    sincosf(ang, &s, &c);
    const float* p = ktmp + (size_t)t * (KVH * DH) + head * DH + d;
    float lo = p[0], hi = p[32];
    kT[(size_t)(head * DH + d) * SEQ + t] = lo * c - hi * s;
    kT[(size_t)(head * DH + d + 32) * SEQ + t] = hi * c + lo * s;
}

// ---------------- attention: one block per (query i, head h) ----------------
__global__ __launch_bounds__(256) void attn_kernel(const float* __restrict__ q,
                                                   const float* __restrict__ kT,
                                                   const float* __restrict__ v,
                                                   float* __restrict__ out) {
    const int i = blockIdx.x;
    const int h = blockIdx.y;
    const int kvh = h >> 2;
    const int tid = threadIdx.x;

    __shared__ float qs[64];
    __shared__ float sc[SEQ];
    __shared__ unsigned hist[256];
    __shared__ int lst[SEQ];
    __shared__ float redf[256];
    __shared__ float redv[4][64];
    __shared__ unsigned s_pref;
    __shared__ int s_k;
    __shared__ int s_cnt;

    if (tid < 64) qs[tid] = q[(size_t)i * DMODEL + h * DH + tid];
    __syncthreads();

    float4 qv[16];
#pragma unroll
    for (int t = 0; t < 16; ++t) qv[t] = *(const float4*)&qs[t * 4];

    const float* kbase = kT + (size_t)(kvh * DH) * SEQ;

    // scores, 4 consecutive j per thread, float4 loads (coalesced over j)
    for (int j0 = tid * 4; j0 < SEQ; j0 += 1024) {
        if (j0 <= i) {
            float ax = 0.f, ay = 0.f, az = 0.f, aw = 0.f;
#pragma unroll
            for (int d4 = 0; d4 < 16; ++d4) {
                float4 qq = qv[d4];
                const float* kp = kbase + (size_t)(d4 * 4) * SEQ + j0;
                float4 k0 = *(const float4*)(kp);
                float4 k1 = *(const float4*)(kp + SEQ);
                float4 k2 = *(const float4*)(kp + 2 * SEQ);
                float4 k3 = *(const float4*)(kp + 3 * SEQ);
                ax += qq.x * k0.x + qq.y * k1.x + qq.z * k2.x + qq.w * k3.x;
                ay += qq.x * k0.y + qq.y * k1.y + qq.z * k2.y + qq.w * k3.y;
                az += qq.x * k0.z + qq.y * k1.z + qq.z * k2.z + qq.w * k3.z;
                aw += qq.x * k0.w + qq.y * k1.w + qq.z * k2.w + qq.w * k3.w;
            }
            sc[j0 + 0] = ax * 0.125f;
            sc[j0 + 1] = ay * 0.125f;
            sc[j0 + 2] = az * 0.125f;
            sc[j0 + 3] = aw * 0.125f;
        }
    }
    __syncthreads();

    // row max over valid j <= i
    float lm = -INFINITY;
    for (int j = tid; j <= i; j += 256) lm = fmaxf(lm, sc[j]);
    redf[tid] = lm;
    __syncthreads();
    for (int off = 128; off > 0; off >>= 1) {
        if (tid < off) redf[tid] = fmaxf(redf[tid], redf[tid + off]);
        __syncthreads();
    }
    const float m = redf[0];
    __syncthreads();

    // exact 64th-largest via 4-pass radix select on ordered-uint domain
    float thr;
    if (i + 1 > TOPK) {
        if (tid == 0) { s_pref = 0u; s_k = TOPK; }
        __syncthreads();
        for (int shift = 24; shift >= 0; shift -= 8) {
            hist[tid] = 0u;
            __syncthreads();
            unsigned pref = s_pref;
            unsigned mask = (shift == 24) ? 0u : (0xFFFFFFFFu << (shift + 8));
            for (int j = tid; j <= i; j += 256) {
                unsigned u = f2u(sc[j]);
                if ((u & mask) == pref) atomicAdd(&hist[(u >> shift) & 255u], 1u);
            }
            __syncthreads();
            if (tid == 0) {
                int kk = s_k, acc = 0, b = 255;
                for (; b > 0; --b) {
                    int c = (int)hist[b];
                    if (acc + c >= kk) break;
                    acc += c;
                }
                s_pref = pref | ((unsigned)b << shift);
                s_k = kk - acc;
            }
            __syncthreads();
        }
        thr = u2f(s_pref);
    } else {
        thr = -INFINITY;  // keep all valid entries
    }

    // compact kept indices, compute weights and denominator
    if (tid == 0) s_cnt = 0;
    __syncthreads();
    float lsum = 0.f;
    for (int j = tid; j <= i; j += 256) {
        float s = sc[j];
        if (s >= thr) {
            float w = expf(s - m);
            lsum += w;
            int p = atomicAdd(&s_cnt, 1);
            lst[p] = j;
            sc[j] = w;   // overwrite score with weight
        }
    }
    redf[tid] = lsum;
    __syncthreads();
    for (int off = 128; off > 0; off >>= 1) {
        if (tid < off) redf[tid] += redf[tid + off];
        __syncthreads();
    }
    const float den = redf[0];
    const int n = s_cnt;

    // AV: 4 groups x 64 dims
    const int d = tid & 63;
    const int g = tid >> 6;
    const float* vbase = v + kvh * DH + d;
    float acc = 0.f;
    for (int l = g; l < n; l += 4) {
        int j = lst[l];
        acc += sc[j] * vbase[(size_t)j * (KVH * DH)];
    }
    redv[g][d] = acc;
    __syncthreads();
    if (g == 0) {
        float r = (redv[0][d] + redv[1][d] + redv[2][d] + redv[3][d]) / den;
        out[(size_t)i * DMODEL + h * DH + d] = r;
    }
}

extern "C" void kernel_launch(void* const* d_in, const int* in_sizes, int n_in,
                              void* d_out, int out_size, void* d_ws, size_t ws_size,
                              hipStream_t stream) {
    const float* x  = (const float*)d_in[0];
    const float* Wq = (const float*)d_in[1];
    const float* Wk = (const float*)d_in[2];
    const float* Wv = (const float*)d_in[3];
    const float* Wo = (const float*)d_in[4];
    float* out = (float*)d_out;

    float* ws = (float*)d_ws;
    float* q    = ws;                               // 2048*1024
    float* kT   = q + (size_t)SEQ * DMODEL;         // 256*2048
    float* vv   = kT + (size_t)(KVH * DH) * SEQ;    // 2048*256
    float* attn = vv + (size_t)SEQ * (KVH * DH);    // 2048*1024
    float* ktmp = attn + (size_t)SEQ * DMODEL;      // 2048*256

    dim3 blk(256);

    // QKV projections
    gemm_abT<<<dim3(DMODEL / 64, SEQ / 64), blk, 0, stream>>>(x, Wq, q, SEQ, DMODEL, DMODEL);
    gemm_abT<<<dim3((KVH * DH) / 64, SEQ / 64), blk, 0, stream>>>(x, Wk, ktmp, SEQ, KVH * DH, DMODEL);
    gemm_abT<<<dim3((KVH * DH) / 64, SEQ / 64), blk, 0, stream>>>(x, Wv, vv, SEQ, KVH * DH, DMODEL);

    // RoPE
    rope_q_kernel<<<(SEQ * QH * 32 + 255) / 256, blk, 0, stream>>>(q);
    rope_k_t_kernel<<<(SEQ * KVH * 32 + 255) / 256, blk, 0, stream>>>(ktmp, kT);

    // attention with exact top-64 threshold
    attn_kernel<<<dim3(SEQ, QH), blk, 0, stream>>>(q, kT, vv, attn);

    // output projection
    gemm_abT<<<dim3(DMODEL / 64, SEQ / 64), blk, 0, stream>>>(attn, Wo, out, SEQ, DMODEL, DMODEL);
}

// Round 2
// 723.760 us; speedup vs baseline: 6.8732x; 6.8732x over previous
//
#include <hip/hip_runtime.h>
#include <hip/hip_bf16.h>
#include <math.h>

#define SEQ 2048
#define DMODEL 1024
#define QH 16
#define KVH 4
#define DH 64
#define TOPK 64
#define KV_D (KVH * DH)   // 256

// ---------------- monotone float->uint mapping for exact rank selection ----------------
__device__ __forceinline__ unsigned f2u(float f) {
    unsigned u = __float_as_uint(f);
    return (u & 0x80000000u) ? ~u : (u | 0x80000000u);
}

// ---------------- tiled f32 GEMM: C[M,N] = A[M,K] * B[N,K]^T ----------------
__global__ __launch_bounds__(256) void gemm_abT(const float* __restrict__ A,
                                                const float* __restrict__ B,
                                                float* __restrict__ C,
                                                int M, int N, int K) {
    __shared__ float As[16][68];
    __shared__ float Bs[16][68];
    const int tid = threadIdx.x;
    const int m0 = blockIdx.y * 64;
    const int n0 = blockIdx.x * 64;
    const int lr = tid >> 2;          // 0..63
    const int lk = (tid & 3) << 2;    // 0,4,8,12
    const int tx = tid & 15;
    const int ty = tid >> 4;

    float acc[4][4];
#pragma unroll
    for (int a = 0; a < 4; ++a)
#pragma unroll
        for (int b = 0; b < 4; ++b) acc[a][b] = 0.f;

    const float* Ap = A + (size_t)(m0 + lr) * K + lk;
    const float* Bp = B + (size_t)(n0 + lr) * K + lk;

    for (int k0 = 0; k0 < K; k0 += 16) {
        float4 a4 = *(const float4*)(Ap + k0);
        float4 b4 = *(const float4*)(Bp + k0);
        As[lk + 0][lr] = a4.x; As[lk + 1][lr] = a4.y;
        As[lk + 2][lr] = a4.z; As[lk + 3][lr] = a4.w;
        Bs[lk + 0][lr] = b4.x; Bs[lk + 1][lr] = b4.y;
        Bs[lk + 2][lr] = b4.z; Bs[lk + 3][lr] = b4.w;
        __syncthreads();
#pragma unroll
        for (int kk = 0; kk < 16; ++kk) {
            float a0 = As[kk][ty * 4 + 0], a1 = As[kk][ty * 4 + 1];
            float a2 = As[kk][ty * 4 + 2], a3 = As[kk][ty * 4 + 3];
            float b0 = Bs[kk][tx * 4 + 0], b1 = Bs[kk][tx * 4 + 1];
            float b2 = Bs[kk][tx * 4 + 2], b3 = Bs[kk][tx * 4 + 3];
            acc[0][0] += a0 * b0; acc[0][1] += a0 * b1; acc[0][2] += a0 * b2; acc[0][3] += a0 * b3;
            acc[1][0] += a1 * b0; acc[1][1] += a1 * b1; acc[1][2] += a1 * b2; acc[1][3] += a1 * b3;
            acc[2][0] += a2 * b0; acc[2][1] += a2 * b1; acc[2][2] += a2 * b2; acc[2][3] += a2 * b3;
            acc[3][0] += a3 * b0; acc[3][1] += a3 * b1; acc[3][2] += a3 * b2; acc[3][3] += a3 * b3;
        }
        __syncthreads();
    }
#pragma unroll
    for (int ii = 0; ii < 4; ++ii)
#pragma unroll
        for (int jj = 0; jj < 4; ++jj)
            C[(size_t)(m0 + ty * 4 + ii) * N + n0 + tx * 4 + jj] = acc[ii][jj];
}

// ---------------- RoPE on q, in place ----------------
__global__ __launch_bounds__(256) void rope_q_kernel(float* __restrict__ q) {
    int idx = blockIdx.x * 256 + threadIdx.x;
    if (idx >= SEQ * QH * 32) return;
    int t = idx >> 9;
    int rem = idx & 511;
    int head = rem >> 5;
    int d = rem & 31;
    float inv = powf(10000.0f, -(float)d * (1.0f / 32.0f));
    float ang = (float)t * inv;
    float s, c;
    sincosf(ang, &s, &c);
    float* p = q + (size_t)t * DMODEL + head * DH + d;
    float lo = p[0], hi = p[32];
    p[0] = lo * c - hi * s;
    p[32] = hi * c + lo * s;
}

// ---------------- RoPE on k + transpose to kT[(head*64+d)][t] ----------------
__global__ __launch_bounds__(256) void rope_k_t_kernel(const float* __restrict__ ktmp,
                                                       float* __restrict__ kT) {
    int idx = blockIdx.x * 256 + threadIdx.x;
    if (idx >= SEQ * KVH * 32) return;
    int t = idx >> 7;
    int rem = idx & 127;
    int head = rem >> 5;
    int d = rem & 31;
    float inv = powf(10000.0f, -(float)d * (1.0f / 32.0f));
    float ang = (float)t * inv;
    float s, c;
    sincosf(ang, &s, &c);
    const float* p = ktmp + (size_t)t * KV_D + head * DH + d;
    float lo = p[0], hi = p[32];
    kT[(size_t)(head * DH + d) * SEQ + t] = lo * c - hi * s;
    kT[(size_t)(head * DH + d + 32) * SEQ + t] = hi * c + lo * s;
}

// ---------------- AV helper: process one 64-lane group of weights ----------------
__device__ __forceinline__ void av_group(float w, int jbase, const float* __restrict__ vb,
                                         float& acc) {
    unsigned long long mk = __ballot(w > 0.f);
    while (mk) {
        int l = __ffsll((unsigned long long)mk) - 1;
        mk &= mk - 1;
        float wj = __shfl(w, l, 64);
        acc += wj * vb[(size_t)(jbase + l * 4) * KV_D];
    }
}

// ---------------- attention: one WAVE per (query i, head h); no LDS, no syncthreads ----------------
__global__ __launch_bounds__(256, 3) void attn_wave(const float* __restrict__ q,
                                                    const float* __restrict__ kT,
                                                    const float* __restrict__ v,
                                                    float* __restrict__ out) {
    const int lane = threadIdx.x & 63;
    const int r = blockIdx.x * 4 + (threadIdx.x >> 6);
    const int h = r >> 11;
    const int i = r & (SEQ - 1);
    const int kvh = h >> 2;

    const float* qp = q + (size_t)i * DMODEL + h * DH;   // wave-uniform address
    const float* kbase = kT + (size_t)(kvh * DH) * SEQ;

    // ---- scores: lane owns j = c*256 + lane*4 + {0..3} ----
    float4 sc[8];
#pragma unroll
    for (int c = 0; c < 8; ++c) {
        sc[c] = make_float4(-INFINITY, -INFINITY, -INFINITY, -INFINITY);
        if (c * 256 <= i) {                       // wave-uniform branch
            const int j0 = c * 256 + lane * 4;
            const float* kp = kbase + j0;
            float ax = 0.f, ay = 0.f, az = 0.f, aw = 0.f;
#pragma unroll 8
            for (int d = 0; d < 64; ++d) {
                float qd = qp[d];                 // uniform -> s_load
                float4 k4 = *(const float4*)kp;
                kp += SEQ;
                ax += qd * k4.x; ay += qd * k4.y;
                az += qd * k4.z; aw += qd * k4.w;
            }
            sc[c].x = (j0 + 0 <= i) ? ax * 0.125f : -INFINITY;
            sc[c].y = (j0 + 1 <= i) ? ay * 0.125f : -INFINITY;
            sc[c].z = (j0 + 2 <= i) ? az * 0.125f : -INFINITY;
            sc[c].w = (j0 + 3 <= i) ? aw * 0.125f : -INFINITY;
        }
    }

    // ---- row max (valid entries; invalid are -inf) ----
    float m = -INFINITY;
#pragma unroll
    for (int c = 0; c < 8; ++c)
        m = fmaxf(m, fmaxf(fmaxf(sc[c].x, sc[c].y), fmaxf(sc[c].z, sc[c].w)));
#pragma unroll
    for (int o = 32; o > 0; o >>= 1) m = fmaxf(m, __shfl_xor(m, o, 64));

    // ---- ordered-uint view; invalid entries -> 0 (below any finite score) ----
    uint4 uv[8];
#pragma unroll
    for (int c = 0; c < 8; ++c) {
        uv[c].x = (sc[c].x == -INFINITY) ? 0u : f2u(sc[c].x);
        uv[c].y = (sc[c].y == -INFINITY) ? 0u : f2u(sc[c].y);
        uv[c].z = (sc[c].z == -INFINITY) ? 0u : f2u(sc[c].z);
        uv[c].w = (sc[c].w == -INFINITY) ? 0u : f2u(sc[c].w);
    }

    // ---- exact 64th-largest: max p with count(u >= p) >= 64 (bitwise search) ----
    unsigned p = 1u;                 // i+1 <= 64: keep every valid entry (u >= 0x00800000 > 1)
    if (i >= TOPK) {
        p = 0u;
        for (int b = 31; b >= 0; --b) {
            unsigned cand = p | (1u << b);
            int cnt = 0;
#pragma unroll
            for (int c = 0; c < 8; ++c) {
                cnt += (uv[c].x >= cand) + (uv[c].y >= cand) +
                       (uv[c].z >= cand) + (uv[c].w >= cand);
            }
#pragma unroll
            for (int o = 32; o > 0; o >>= 1) cnt += __shfl_xor(cnt, o, 64);
            if (cnt >= TOPK) p = cand;           // cnt uniform after reduce
        }
    }

    // ---- weights: keep u >= p (exact tie semantics), softmax numerators ----
    float lsum = 0.f;
#pragma unroll
    for (int c = 0; c < 8; ++c) {
        float wx = (uv[c].x >= p) ? __expf(sc[c].x - m) : 0.f;
        float wy = (uv[c].y >= p) ? __expf(sc[c].y - m) : 0.f;
        float wz = (uv[c].z >= p) ? __expf(sc[c].z - m) : 0.f;
        float ww = (uv[c].w >= p) ? __expf(sc[c].w - m) : 0.f;
        sc[c].x = wx; sc[c].y = wy; sc[c].z = wz; sc[c].w = ww;
        lsum += (wx + wy) + (wz + ww);
    }
    float den = lsum;
#pragma unroll
    for (int o = 32; o > 0; o >>= 1) den += __shfl_xor(den, o, 64);

    // ---- AV: ballot kept weights, broadcast, accumulate; lane = output dim ----
    float acc = 0.f;
    const float* vb = v + kvh * DH + lane;       // v layout [j][KV_D]
#pragma unroll
    for (int c = 0; c < 8; ++c) {
        if (c * 256 <= i) {                      // wave-uniform
            av_group(sc[c].x, c * 256 + 0, vb, acc);
            av_group(sc[c].y, c * 256 + 1, vb, acc);
            av_group(sc[c].z, c * 256 + 2, vb, acc);
            av_group(sc[c].w, c * 256 + 3, vb, acc);
        }
    }

    out[(size_t)i * DMODEL + h * DH + lane] = acc / den;
}

extern "C" void kernel_launch(void* const* d_in, const int* in_sizes, int n_in,
                              void* d_out, int out_size, void* d_ws, size_t ws_size,
                              hipStream_t stream) {
    const float* x  = (const float*)d_in[0];
    const float* Wq = (const float*)d_in[1];
    const float* Wk = (const float*)d_in[2];
    const float* Wv = (const float*)d_in[3];
    const float* Wo = (const float*)d_in[4];
    float* out = (float*)d_out;

    float* ws = (float*)d_ws;
    float* q    = ws;                               // 2048*1024
    float* kT   = q + (size_t)SEQ * DMODEL;         // 256*2048
    float* vv   = kT + (size_t)KV_D * SEQ;          // 2048*256
    float* attn = vv + (size_t)SEQ * KV_D;          // 2048*1024
    float* ktmp = attn + (size_t)SEQ * DMODEL;      // 2048*256

    dim3 blk(256);

    // QKV projections
    gemm_abT<<<dim3(DMODEL / 64, SEQ / 64), blk, 0, stream>>>(x, Wq, q, SEQ, DMODEL, DMODEL);
    gemm_abT<<<dim3(KV_D / 64, SEQ / 64), blk, 0, stream>>>(x, Wk, ktmp, SEQ, KV_D, DMODEL);
    gemm_abT<<<dim3(KV_D / 64, SEQ / 64), blk, 0, stream>>>(x, Wv, vv, SEQ, KV_D, DMODEL);

    // RoPE
    rope_q_kernel<<<(SEQ * QH * 32 + 255) / 256, blk, 0, stream>>>(q);
    rope_k_t_kernel<<<(SEQ * KVH * 32 + 255) / 256, blk, 0, stream>>>(ktmp, kT);

    // attention: one wave per (i, h) row
    attn_wave<<<(SEQ * QH) / 4, blk, 0, stream>>>(q, kT, vv, attn);

    // output projection
    gemm_abT<<<dim3(DMODEL / 64, SEQ / 64), blk, 0, stream>>>(attn, Wo, out, SEQ, DMODEL, DMODEL);
}